// Round 6
// baseline (150.193 us; speedup 1.0000x reference)
//
#include <hip/hip_runtime.h>
#include <math.h>

// ---------------------------------------------------------------------------
// Scattering (J=2,L=8,N=32) + GroupNorm(27) + Linear(15552->10), round 6.
// TWO kernels; u0f never leaves LDS:
//   k_scat  (1152 blocks x 64): blocks 0..767 per (bc,pair): fft2(x) inline,
//       2 u0f planes in LDS, s0/s1a, then 16 order-2 (t1,t2) planes in 4
//       rounds of 4 -> s2.  blocks 768..1151 per (bc,half): fft2(x) inline,
//       j1=1 4 t2-planes -> s1b.
//   k_gnlin (64 blocks x 256): GroupNorm + GEMV(float4) -> out
// ---------------------------------------------------------------------------

constexpr float C32T[32] = {
  1.0000000000f, 0.9807852804f, 0.9238795325f, 0.8314696123f,
  0.7071067812f, 0.5555702330f, 0.3826834324f, 0.1950903220f,
  0.0000000000f,-0.1950903220f,-0.3826834324f,-0.5555702330f,
 -0.7071067812f,-0.8314696123f,-0.9238795325f,-0.9807852804f,
 -1.0000000000f,-0.9807852804f,-0.9238795325f,-0.8314696123f,
 -0.7071067812f,-0.5555702330f,-0.3826834324f,-0.1950903220f,
  0.0000000000f, 0.1950903220f, 0.3826834324f, 0.5555702330f,
  0.7071067812f, 0.8314696123f, 0.9238795325f, 0.9807852804f };
constexpr float S32T[32] = {
  0.0000000000f, 0.1950903220f, 0.3826834324f, 0.5555702330f,
  0.7071067812f, 0.8314696123f, 0.9238795325f, 0.9807852804f,
  1.0000000000f, 0.9807852804f, 0.9238795325f, 0.8314696123f,
  0.7071067812f, 0.5555702330f, 0.3826834324f, 0.1950903220f,
  0.0000000000f,-0.1950903220f,-0.3826834324f,-0.5555702330f,
 -0.7071067812f,-0.8314696123f,-0.9238795325f,-0.9807852804f,
 -1.0000000000f,-0.9807852804f,-0.9238795325f,-0.8314696123f,
 -0.7071067812f,-0.5555702330f,-0.3826834324f,-0.1950903220f };

template<int N, bool INV>
__device__ __forceinline__ void fft1d(float2 (&a)[N]) {
  constexpr int LOG = (N == 32) ? 5 : ((N == 16) ? 4 : 3);
  #pragma unroll
  for (int i = 0; i < N; ++i) {
    int j = 0;
    #pragma unroll
    for (int bn = 0; bn < LOG; ++bn) j |= ((i >> bn) & 1) << (LOG - 1 - bn);
    if (j > i) { float2 t = a[i]; a[i] = a[j]; a[j] = t; }
  }
  #pragma unroll
  for (int s = 1; s <= LOG; ++s) {
    const int half  = 1 << (s - 1);
    const int tstep = 32 >> s;
    #pragma unroll
    for (int i = 0; i < N; i += (1 << s)) {
      #pragma unroll
      for (int k = 0; k < half; ++k) {
        const int   ti = k * tstep;
        const float wr = C32T[ti];
        const float wi = INV ? S32T[ti] : -S32T[ti];
        const float2 u = a[i + k];
        const float2 v = a[i + k + half];
        const float tr = v.x * wr - v.y * wi;
        const float tq = v.x * wi + v.y * wr;
        a[i + k]        = make_float2(u.x + tr, u.y + tq);
        a[i + k + half] = make_float2(u.x - tr, u.y - tq);
      }
    }
  }
}

template<int N, bool INV>
__device__ __forceinline__ void fft_row(float* re, float* im, int row, int LD) {
  float2 a[N];
  #pragma unroll
  for (int i = 0; i < N; ++i) a[i] = make_float2(re[row * LD + i], im[row * LD + i]);
  fft1d<N, INV>(a);
  #pragma unroll
  for (int i = 0; i < N; ++i) { re[row * LD + i] = a[i].x; im[row * LD + i] = a[i].y; }
}

template<int N, bool INV>
__device__ __forceinline__ void fft_col(float* re, float* im, int col, int LD) {
  float2 a[N];
  #pragma unroll
  for (int i = 0; i < N; ++i) a[i] = make_float2(re[i * LD + col], im[i * LD + col]);
  fft1d<N, INV>(a);
  #pragma unroll
  for (int i = 0; i < N; ++i) { re[i * LD + col] = a[i].x; im[i * LD + col] = a[i].y; }
}

// ---------------------------------------------------------------------------
// k_scat: grid 1152, block 64 (single wave; barriers near-free).
// ---------------------------------------------------------------------------
__global__ __launch_bounds__(64) void k_scat(
    const float* __restrict__ x, const float* __restrict__ psi0,
    const float* __restrict__ psi1, const float* __restrict__ phi,
    float* __restrict__ feat)
{
  __shared__ float Xr[1056], Xi[1056];   // xf 32x33
  __shared__ float Ar[2112], Ai[2112];   // 2 x 32x33 u0f planes (u0 blocks)
  __shared__ float Cr[1088], Ci[1088];   // 4 x 16x17 (o2 / j1 pipeline)
  __shared__ float Sr[288],  Si[288];    // 4 x 8x9
  __shared__ float P1[272];              // 16x17 phi at res 1
  const int tid = threadIdx.x;
  const int blk = blockIdx.x;
  const bool is_u0 = blk < 768;
  const int bc = is_u0 ? (blk >> 2) : ((blk - 768) >> 1);

  // ---- load x and phi1, then xf = fft2(x) ----
  for (int e = tid; e < 1024; e += 64) {
    Xr[(e >> 5) * 33 + (e & 31)] = x[bc * 1024 + e];
    Xi[(e >> 5) * 33 + (e & 31)] = 0.0f;
  }
  for (int e = tid; e < 256; e += 64) {
    const int u = e >> 4, v = e & 15;
    P1[u * 17 + v] = 0.25f * (phi[u * 32 + v] + phi[u * 32 + v + 16] +
                              phi[(u + 16) * 32 + v] + phi[(u + 16) * 32 + v + 16]);
  }
  __syncthreads();
  if (tid < 32) fft_row<32, false>(Xr, Xi, tid, 33);
  __syncthreads();
  if (tid < 32) fft_col<32, false>(Xr, Xi, tid, 33);
  __syncthreads();

  if (is_u0) {
    // ==== u0 path: planes p0, p0+1; then their 16 order-2 planes ====
    const int p0 = (blk & 3) * 2;
    for (int e = tid; e < 2048; e += 64) {
      const int q = e >> 10, rc = e & 1023, r = rc >> 5, c = rc & 31;
      const float ps = psi0[(p0 + q) * 1024 + rc];
      Ar[q * 1056 + r * 33 + c] = Xr[r * 33 + c] * ps;
      Ai[q * 1056 + r * 33 + c] = Xi[r * 33 + c] * ps;
    }
    __syncthreads();
    { const int q = tid >> 5, r = tid & 31; fft_row<32, true>(Ar + q * 1056, Ai + q * 1056, r, 33); }
    __syncthreads();
    { // cols: inverse, |.|/1024, forward
      const int q = tid >> 5, col = tid & 31;
      float* re = Ar + q * 1056; float* im = Ai + q * 1056;
      float2 a[32];
      #pragma unroll
      for (int i = 0; i < 32; ++i) a[i] = make_float2(re[i * 33 + col], im[i * 33 + col]);
      fft1d<32, true>(a);
      #pragma unroll
      for (int i = 0; i < 32; ++i) {
        const float m = sqrtf(a[i].x * a[i].x + a[i].y * a[i].y) * (1.0f / 1024.0f);
        a[i] = make_float2(m, 0.0f);
      }
      fft1d<32, false>(a);
      #pragma unroll
      for (int i = 0; i < 32; ++i) { re[i * 33 + col] = a[i].x; im[i * 33 + col] = a[i].y; }
    }
    __syncthreads();
    { const int q = tid >> 5, r = tid & 31; fft_row<32, false>(Ar + q * 1056, Ai + q * 1056, r, 33); }
    __syncthreads();
    // u0f planes now live in Ar/Ai for the rest of the block.

    // ---- s1a (planes 0,1) and s0 (plane 2, pair 0 only) ----
    const int nsp = (p0 == 0) ? 3 : 2;
    for (int e = tid; e < nsp * 64; e += 64) {
      const int p = e >> 6, u = (e >> 3) & 7, v = e & 7;
      float sr = 0.f, si = 0.f;
      #pragma unroll
      for (int i2 = 0; i2 < 4; ++i2)
        #pragma unroll
        for (int j2 = 0; j2 < 4; ++j2) {
          const int r = u + 8 * i2, c = v + 8 * j2;
          const float ph = phi[r * 32 + c];
          float vr, vi;
          if (p == 2) { vr = Xr[r * 33 + c]; vi = Xi[r * 33 + c]; }
          else        { vr = Ar[p * 1056 + r * 33 + c]; vi = Ai[p * 1056 + r * 33 + c]; }
          sr += vr * ph; si += vi * ph;
        }
      Sr[p * 72 + u * 9 + v] = sr * 0.0625f;
      Si[p * 72 + u * 9 + v] = si * 0.0625f;
    }
    __syncthreads();
    if (tid < nsp * 8) { const int p = tid >> 3, r = tid & 7; fft_row<8, true>(Sr + p * 72, Si + p * 72, r, 9); }
    __syncthreads();
    if (tid < nsp * 8) {
      const int p = tid >> 3, col = tid & 7;
      float2 a[8];
      #pragma unroll
      for (int i = 0; i < 8; ++i) a[i] = make_float2(Sr[p * 72 + i * 9 + col], Si[p * 72 + i * 9 + col]);
      fft1d<8, true>(a);
      const int ch = (p == 2) ? 0 : (1 + p0 + p);
      float* fo = feat + ((size_t)bc * 81 + ch) * 64;
      #pragma unroll
      for (int i = 0; i < 8; ++i) fo[i * 8 + col] = a[i].x * (1.0f / 64.0f);
    }
    __syncthreads();   // Sr/Si about to be reused by order-2 rounds

    // ---- order 2: 16 (t1,t2) planes in 4 rounds of 4, source u0f in LDS ----
    for (int round = 0; round < 4; ++round) {
      const int t1l = round >> 1;            // 0,0,1,1
      const int t2b = (round & 1) * 4;       // 0,4,0,4
      const float* ur = Ar + t1l * 1056;
      const float* ui = Ai + t1l * 1056;
      for (int e = tid; e < 1024; e += 64) {
        const int q = e >> 8, u = (e >> 4) & 15, v = e & 15;
        const int t2 = t2b + q;
        float sr = 0.f, si = 0.f;
        #pragma unroll
        for (int i2 = 0; i2 < 2; ++i2)
          #pragma unroll
          for (int j2 = 0; j2 < 2; ++j2) {
            const int r = u + 16 * i2, c = v + 16 * j2;
            const float ps = psi1[t2 * 1024 + r * 32 + c];
            sr += ur[r * 33 + c] * ps;
            si += ui[r * 33 + c] * ps;
          }
        Cr[q * 272 + u * 17 + v] = 0.25f * sr;
        Ci[q * 272 + u * 17 + v] = 0.25f * si;
      }
      __syncthreads();
      { const int q = tid >> 4, r = tid & 15; fft_row<16, true>(Cr + q * 272, Ci + q * 272, r, 17); }
      __syncthreads();
      { const int q = tid >> 4, col = tid & 15;
        float* re = Cr + q * 272; float* im = Ci + q * 272;
        float2 a[16];
        #pragma unroll
        for (int i = 0; i < 16; ++i) a[i] = make_float2(re[i * 17 + col], im[i * 17 + col]);
        fft1d<16, true>(a);
        #pragma unroll
        for (int i = 0; i < 16; ++i) {
          const float m = sqrtf(a[i].x * a[i].x + a[i].y * a[i].y) * (1.0f / 256.0f);
          a[i] = make_float2(m, 0.0f);
        }
        fft1d<16, false>(a);
        #pragma unroll
        for (int i = 0; i < 16; ++i) { re[i * 17 + col] = a[i].x; im[i * 17 + col] = a[i].y; }
      }
      __syncthreads();
      { const int q = tid >> 4, r = tid & 15; fft_row<16, false>(Cr + q * 272, Ci + q * 272, r, 17); }
      __syncthreads();
      for (int e = tid; e < 256; e += 64) {
        const int q = e >> 6, u = (e >> 3) & 7, v = e & 7;
        float sr = 0.f, si = 0.f;
        #pragma unroll
        for (int i2 = 0; i2 < 2; ++i2)
          #pragma unroll
          for (int j2 = 0; j2 < 2; ++j2) {
            const int r = u + 8 * i2, c = v + 8 * j2;
            const float ph = P1[r * 17 + c];
            sr += Cr[q * 272 + r * 17 + c] * ph;
            si += Ci[q * 272 + r * 17 + c] * ph;
          }
        Sr[q * 72 + u * 9 + v] = 0.25f * sr;
        Si[q * 72 + u * 9 + v] = 0.25f * si;
      }
      __syncthreads();
      if (tid < 32) { const int q = tid >> 3, r = tid & 7; fft_row<8, true>(Sr + q * 72, Si + q * 72, r, 9); }
      __syncthreads();
      if (tid < 32) {
        const int q = tid >> 3, col = tid & 7;
        float2 a[8];
        #pragma unroll
        for (int i = 0; i < 8; ++i) a[i] = make_float2(Sr[q * 72 + i * 9 + col], Si[q * 72 + i * 9 + col]);
        fft1d<8, true>(a);
        const int ch = 17 + (p0 + t1l) * 8 + t2b + q;
        float* fo = feat + ((size_t)bc * 81 + ch) * 64;
        #pragma unroll
        for (int i = 0; i < 8; ++i) fo[i * 8 + col] = a[i].x * (1.0f / 64.0f);
      }
      __syncthreads();
    }
  } else {
    // ==== j1=1 path: 4 t2-planes, 16x16 modulus pipeline -> s1b ====
    const int t2b = ((blk - 768) & 1) * 4;
    for (int e = tid; e < 1024; e += 64) {
      const int q = e >> 8, u = (e >> 4) & 15, v = e & 15;
      const int t2 = t2b + q;
      float sr = 0.f, si = 0.f;
      #pragma unroll
      for (int i2 = 0; i2 < 2; ++i2)
        #pragma unroll
        for (int j2 = 0; j2 < 2; ++j2) {
          const int r = u + 16 * i2, c = v + 16 * j2;
          const float ps = psi1[t2 * 1024 + r * 32 + c];
          sr += Xr[r * 33 + c] * ps;
          si += Xi[r * 33 + c] * ps;
        }
      Cr[q * 272 + u * 17 + v] = 0.25f * sr;
      Ci[q * 272 + u * 17 + v] = 0.25f * si;
    }
    __syncthreads();
    { const int q = tid >> 4, r = tid & 15; fft_row<16, true>(Cr + q * 272, Ci + q * 272, r, 17); }
    __syncthreads();
    { const int q = tid >> 4, col = tid & 15;
      float* re = Cr + q * 272; float* im = Ci + q * 272;
      float2 a[16];
      #pragma unroll
      for (int i = 0; i < 16; ++i) a[i] = make_float2(re[i * 17 + col], im[i * 17 + col]);
      fft1d<16, true>(a);
      #pragma unroll
      for (int i = 0; i < 16; ++i) {
        const float m = sqrtf(a[i].x * a[i].x + a[i].y * a[i].y) * (1.0f / 256.0f);
        a[i] = make_float2(m, 0.0f);
      }
      fft1d<16, false>(a);
      #pragma unroll
      for (int i = 0; i < 16; ++i) { re[i * 17 + col] = a[i].x; im[i * 17 + col] = a[i].y; }
    }
    __syncthreads();
    { const int q = tid >> 4, r = tid & 15; fft_row<16, false>(Cr + q * 272, Ci + q * 272, r, 17); }
    __syncthreads();
    for (int e = tid; e < 256; e += 64) {
      const int q = e >> 6, u = (e >> 3) & 7, v = e & 7;
      float sr = 0.f, si = 0.f;
      #pragma unroll
      for (int i2 = 0; i2 < 2; ++i2)
        #pragma unroll
        for (int j2 = 0; j2 < 2; ++j2) {
          const int r = u + 8 * i2, c = v + 8 * j2;
          const float ph = P1[r * 17 + c];
          sr += Cr[q * 272 + r * 17 + c] * ph;
          si += Ci[q * 272 + r * 17 + c] * ph;
        }
      Sr[q * 72 + u * 9 + v] = 0.25f * sr;
      Si[q * 72 + u * 9 + v] = 0.25f * si;
    }
    __syncthreads();
    if (tid < 32) { const int q = tid >> 3, r = tid & 7; fft_row<8, true>(Sr + q * 72, Si + q * 72, r, 9); }
    __syncthreads();
    if (tid < 32) {
      const int q = tid >> 3, col = tid & 7;
      float2 a[8];
      #pragma unroll
      for (int i = 0; i < 8; ++i) a[i] = make_float2(Sr[q * 72 + i * 9 + col], Si[q * 72 + i * 9 + col]);
      fft1d<8, true>(a);
      float* fo = feat + ((size_t)bc * 81 + 9 + t2b + q) * 64;
      #pragma unroll
      for (int i = 0; i < 8; ++i) fo[i * 8 + col] = a[i].x * (1.0f / 64.0f);
    }
  }
}

// ---------------------------------------------------------------------------
// k_gnlin: GroupNorm(27) + Linear(15552->10). grid 64, block 256.
// ---------------------------------------------------------------------------
__global__ __launch_bounds__(256) void k_gnlin(
    const float* __restrict__ feat, const float* __restrict__ gamma,
    const float* __restrict__ beta, const float* __restrict__ W,
    const float* __restrict__ bias, float* __restrict__ out)
{
  __shared__ float F[15552];
  __shared__ float gmu[27], grs[27];
  __shared__ float red[40];
  const int tid = threadIdx.x, b = blockIdx.x;
  const float* fp = feat + (size_t)b * 15552;
  for (int e = tid; e < 15552; e += 256) F[e] = fp[e];
  __syncthreads();
  if (tid < 216) {
    const int g = tid >> 3, l8 = tid & 7;
    float s = 0.f, ss = 0.f;
    for (int e = l8; e < 576; e += 8) { const float v = F[g * 576 + e]; s += v; ss += v * v; }
    #pragma unroll
    for (int off = 1; off < 8; off <<= 1) { s += __shfl_down(s, off); ss += __shfl_down(ss, off); }
    if (l8 == 0) {
      const float mu = s * (1.0f / 576.0f);
      gmu[g] = mu;
      grs[g] = rsqrtf(ss * (1.0f / 576.0f) - mu * mu + 1e-5f);
    }
  }
  __syncthreads();
  for (int e = tid; e < 15552; e += 256) {
    const int ch = e >> 6, g = ch / 9;
    F[e] = (F[e] - gmu[g]) * grs[g] * gamma[ch] + beta[ch];
  }
  __syncthreads();
  float acc[10];
  #pragma unroll
  for (int k = 0; k < 10; ++k) acc[k] = 0.f;
  const float4* F4 = reinterpret_cast<const float4*>(F);
  for (int i4 = tid; i4 < 3888; i4 += 256) {
    const float4 f = F4[i4];
    #pragma unroll
    for (int k = 0; k < 10; ++k) {
      const float4 w = *reinterpret_cast<const float4*>(&W[(size_t)k * 15552 + i4 * 4]);
      acc[k] = fmaf(f.x, w.x, fmaf(f.y, w.y, fmaf(f.z, w.z, fmaf(f.w, w.w, acc[k]))));
    }
  }
  #pragma unroll
  for (int k = 0; k < 10; ++k) {
    float v = acc[k];
    #pragma unroll
    for (int off = 32; off > 0; off >>= 1) v += __shfl_down(v, off);
    if ((tid & 63) == 0) red[(tid >> 6) * 10 + k] = v;
  }
  __syncthreads();
  if (tid < 10) out[b * 10 + tid] = red[tid] + red[10 + tid] + red[20 + tid] + red[30 + tid] + bias[tid];
}

// ---------------------------------------------------------------------------
extern "C" void kernel_launch(void* const* d_in, const int* in_sizes, int n_in,
                              void* d_out, int out_size, void* d_ws, size_t ws_size,
                              hipStream_t stream) {
  (void)in_sizes; (void)n_in; (void)out_size; (void)ws_size;
  const float* x     = (const float*)d_in[0];
  const float* psi0  = (const float*)d_in[1];
  const float* psi1  = (const float*)d_in[2];
  const float* phi   = (const float*)d_in[3];
  const float* gamma = (const float*)d_in[4];
  const float* beta  = (const float*)d_in[5];
  const float* W     = (const float*)d_in[6];
  const float* bias  = (const float*)d_in[7];
  float* out = (float*)d_out;

  float* feat = (float*)d_ws;   // 64*15552 f32 = 4 MB (only ws use)

  hipLaunchKernelGGL(k_scat,  dim3(1152), dim3(64),  0, stream, x, psi0, psi1, phi, feat);
  hipLaunchKernelGGL(k_gnlin, dim3(64),   dim3(256), 0, stream, feat, gamma, beta, W, bias, out);
}

// Round 7
// 128.068 us; speedup vs baseline: 1.1728x; 1.1728x over previous
//
#include <hip/hip_runtime.h>
#include <math.h>

// ---------------------------------------------------------------------------
// Scattering (J=2,L=8,N=32) + GroupNorm(27) + Linear(15552->10), round 7.
// Same 2-kernel structure as round 6, but CODE-SIZE-MINIMIZED: one fft32
// instance and one fft16 instance via table-driven pass loops (#pragma
// unroll 1, branch-free pass params). Theory: r6's 110us k_scat was
// I-cache-thrash-bound (~17k instrs vs 32KB I$), not occupancy-bound.
// k_gnlin: 1024 threads + float4 loads.
// ---------------------------------------------------------------------------

constexpr float C32T[32] = {
  1.0000000000f, 0.9807852804f, 0.9238795325f, 0.8314696123f,
  0.7071067812f, 0.5555702330f, 0.3826834324f, 0.1950903220f,
  0.0000000000f,-0.1950903220f,-0.3826834324f,-0.5555702330f,
 -0.7071067812f,-0.8314696123f,-0.9238795325f,-0.9807852804f,
 -1.0000000000f,-0.9807852804f,-0.9238795325f,-0.8314696123f,
 -0.7071067812f,-0.5555702330f,-0.3826834324f,-0.1950903220f,
  0.0000000000f, 0.1950903220f, 0.3826834324f, 0.5555702330f,
  0.7071067812f, 0.8314696123f, 0.9238795325f, 0.9807852804f };
constexpr float S32T[32] = {
  0.0000000000f, 0.1950903220f, 0.3826834324f, 0.5555702330f,
  0.7071067812f, 0.8314696123f, 0.9238795325f, 0.9807852804f,
  1.0000000000f, 0.9807852804f, 0.9238795325f, 0.8314696123f,
  0.7071067812f, 0.5555702330f, 0.3826834324f, 0.1950903220f,
  0.0000000000f,-0.1950903220f,-0.3826834324f,-0.5555702330f,
 -0.7071067812f,-0.8314696123f,-0.9238795325f,-0.9807852804f,
 -1.0000000000f,-0.9807852804f,-0.9238795325f,-0.8314696123f,
 -0.7071067812f,-0.5555702330f,-0.3826834324f,-0.1950903220f };

// N-point FFT, runtime direction: sgn=+1 inverse kernel, sgn=-1 forward.
template<int N>
__device__ __forceinline__ void fftN(float2 (&a)[N], float sgn) {
  constexpr int LOG = (N == 32) ? 5 : ((N == 16) ? 4 : 3);
  #pragma unroll
  for (int i = 0; i < N; ++i) {
    int j = 0;
    #pragma unroll
    for (int bn = 0; bn < LOG; ++bn) j |= ((i >> bn) & 1) << (LOG - 1 - bn);
    if (j > i) { float2 t = a[i]; a[i] = a[j]; a[j] = t; }
  }
  #pragma unroll
  for (int s = 1; s <= LOG; ++s) {
    const int half  = 1 << (s - 1);
    const int tstep = 32 >> s;
    #pragma unroll
    for (int i = 0; i < N; i += (1 << s)) {
      #pragma unroll
      for (int k = 0; k < half; ++k) {
        const int   ti = k * tstep;
        const float wr = C32T[ti];
        const float wi = sgn * S32T[ti];
        const float2 u = a[i + k];
        const float2 v = a[i + k + half];
        const float tr = v.x * wr - v.y * wi;
        const float tq = v.x * wi + v.y * wr;
        a[i + k]        = make_float2(u.x + tr, u.y + tq);
        a[i + k + half] = make_float2(u.x - tr, u.y - tq);
      }
    }
  }
}

// One LDS pass: load N strided points, FFT(sgn); if md: modulus*scale then
// forward FFT (rolled rep loop -> ONE fftN instance); store back.
template<int N>
__device__ __forceinline__ void passN(float* re, float* im, int off, int st,
                                      float sgn, int md, float scale) {
  float2 a[N];
  #pragma unroll
  for (int i = 0; i < N; ++i) a[i] = make_float2(re[off + i * st], im[off + i * st]);
  #pragma unroll 1
  for (int rep = 0; rep <= md; ++rep) {
    fftN<N>(a, rep ? -1.0f : sgn);
    if (rep == 0 && md) {
      #pragma unroll
      for (int i = 0; i < N; ++i) {
        const float m = sqrtf(a[i].x * a[i].x + a[i].y * a[i].y) * scale;
        a[i] = make_float2(m, 0.0f);
      }
    }
  }
  #pragma unroll
  for (int i = 0; i < N; ++i) { re[off + i * st] = a[i].x; im[off + i * st] = a[i].y; }
}

// ---------------------------------------------------------------------------
// k_scat: grid 1152, block 64.
//  blocks 0..767  : (bc, pair): fft2(x), 2 u0f planes in LDS, s0/s1a,
//                   then 4 rounds x 4 order-2 planes -> s2
//  blocks 768..1151: (bc, half): fft2(x), 1 round of 4 j1 planes -> s1b
// ---------------------------------------------------------------------------
__global__ __launch_bounds__(64) void k_scat(
    const float* __restrict__ x, const float* __restrict__ psi0,
    const float* __restrict__ psi1, const float* __restrict__ phi,
    float* __restrict__ feat)
{
  __shared__ float Xr[1056], Xi[1056];   // xf 32x33
  __shared__ float Ar[2112], Ai[2112];   // 2 x 32x33 u0f planes
  __shared__ float Cr[1088], Ci[1088];   // 4 x 16x17
  __shared__ float Sr[288],  Si[288];    // 4 x 8x9
  __shared__ float P1[272];              // 16x17 phi at res 1
  const int tid = threadIdx.x;
  const int blk = blockIdx.x;
  const bool is_u0 = blk < 768;
  const int bc = is_u0 ? (blk >> 2) : ((blk - 768) >> 1);
  const int p0 = is_u0 ? (blk & 3) * 2 : 0;

  // ---- stage x, phi1; xf = fft2(x) (2 passes, one pass32 site) ----
  for (int e = tid; e < 1024; e += 64) {
    Xr[(e >> 5) * 33 + (e & 31)] = x[bc * 1024 + e];
    Xi[(e >> 5) * 33 + (e & 31)] = 0.0f;
  }
  for (int e = tid; e < 256; e += 64) {
    const int u = e >> 4, v = e & 15;
    P1[u * 17 + v] = 0.25f * (phi[u * 32 + v] + phi[u * 32 + v + 16] +
                              phi[(u + 16) * 32 + v] + phi[(u + 16) * 32 + v + 16]);
  }
  __syncthreads();
  #pragma unroll 1
  for (int p = 0; p < 2; ++p) {
    if (tid < 32) {
      const int so = (p == 1) ? 1 : 33, st = 34 - so;
      passN<32>(Xr, Xi, tid * so, st, -1.0f, 0, 0.0f);
    }
    __syncthreads();
  }

  if (is_u0) {
    // ---- u0 pipeline: mult psi0, then 3 passes (one pass32 site) ----
    #pragma unroll 4
    for (int e = tid; e < 2048; e += 64) {
      const int q = e >> 10, rc = e & 1023, r = rc >> 5, c = rc & 31;
      const float ps = psi0[(p0 + q) * 1024 + rc];
      Ar[q * 1056 + r * 33 + c] = Xr[r * 33 + c] * ps;
      Ai[q * 1056 + r * 33 + c] = Xi[r * 33 + c] * ps;
    }
    __syncthreads();
    #pragma unroll 1
    for (int p = 0; p < 3; ++p) {
      const int q = tid >> 5, it = tid & 31;
      const int so = (p == 1) ? 1 : 33, st = 34 - so;
      const float sg = (p == 2) ? -1.0f : 1.0f;
      const int md = (p == 1) ? 1 : 0;
      passN<32>(Ar + q * 1056, Ai + q * 1056, it * so, st, sg, md, 1.0f / 1024.0f);
      __syncthreads();
    }

    // ---- s1a (planes 0,1) + s0 (plane 2, pair 0 only) ----
    const int nsp = (p0 == 0) ? 3 : 2;
    for (int e = tid; e < nsp * 64; e += 64) {
      const int p = e >> 6, u = (e >> 3) & 7, v = e & 7;
      float sr = 0.f, si = 0.f;
      #pragma unroll
      for (int i2 = 0; i2 < 4; ++i2)
        #pragma unroll
        for (int j2 = 0; j2 < 4; ++j2) {
          const int r = u + 8 * i2, c = v + 8 * j2;
          const float ph = phi[r * 32 + c];
          float vr, vi;
          if (p == 2) { vr = Xr[r * 33 + c]; vi = Xi[r * 33 + c]; }
          else        { vr = Ar[p * 1056 + r * 33 + c]; vi = Ai[p * 1056 + r * 33 + c]; }
          sr += vr * ph; si += vi * ph;
        }
      Sr[p * 72 + u * 9 + v] = sr * 0.0625f;
      Si[p * 72 + u * 9 + v] = si * 0.0625f;
    }
    __syncthreads();
    if (tid < nsp * 8) { const int p = tid >> 3, r = tid & 7; passN<8>(Sr + p * 72, Si + p * 72, r * 9, 1, 1.0f, 0, 0.0f); }
    __syncthreads();
    if (tid < nsp * 8) {
      const int p = tid >> 3, col = tid & 7;
      float2 a[8];
      #pragma unroll
      for (int i = 0; i < 8; ++i) a[i] = make_float2(Sr[p * 72 + i * 9 + col], Si[p * 72 + i * 9 + col]);
      fftN<8>(a, 1.0f);
      const int ch = (p == 2) ? 0 : (1 + p0 + p);
      float* fo = feat + ((size_t)bc * 81 + ch) * 64;
      #pragma unroll
      for (int i = 0; i < 8; ++i) fo[i * 8 + col] = a[i].x * (1.0f / 64.0f);
    }
    __syncthreads();
  }

  // ---- 16x16 modulus rounds: u0 blocks 4 rounds (o2), j1 blocks 1 round ----
  const int nr = is_u0 ? 4 : 1;
  #pragma unroll 1
  for (int rd = 0; rd < nr; ++rd) {
    const float *ur, *ui;
    int chb, t2b;
    if (is_u0) {
      const int t1l = rd >> 1;
      t2b = (rd & 1) * 4;
      ur = Ar + t1l * 1056; ui = Ai + t1l * 1056;
      chb = 17 + (p0 + t1l) * 8 + t2b;
    } else {
      t2b = ((blk - 768) & 1) * 4;
      ur = Xr; ui = Xi;
      chb = 9 + t2b;
    }
    // mult + 2x2 fold
    #pragma unroll 4
    for (int e = tid; e < 1024; e += 64) {
      const int q = e >> 8, u = (e >> 4) & 15, v = e & 15;
      const int t2 = t2b + q;
      float sr = 0.f, si = 0.f;
      #pragma unroll
      for (int i2 = 0; i2 < 2; ++i2)
        #pragma unroll
        for (int j2 = 0; j2 < 2; ++j2) {
          const int r = u + 16 * i2, c = v + 16 * j2;
          const float ps = psi1[t2 * 1024 + r * 32 + c];
          sr += ur[r * 33 + c] * ps;
          si += ui[r * 33 + c] * ps;
        }
      Cr[q * 272 + u * 17 + v] = 0.25f * sr;
      Ci[q * 272 + u * 17 + v] = 0.25f * si;
    }
    __syncthreads();
    // 3 fft16 passes (one pass16 site)
    #pragma unroll 1
    for (int p = 0; p < 3; ++p) {
      const int q = tid >> 4, it = tid & 15;
      const int so = (p == 1) ? 1 : 17, st = 18 - so;
      const float sg = (p == 2) ? -1.0f : 1.0f;
      const int md = (p == 1) ? 1 : 0;
      passN<16>(Cr + q * 272, Ci + q * 272, it * so, st, sg, md, 1.0f / 256.0f);
      __syncthreads();
    }
    // low-pass + 2x2 fold -> 8x8
    for (int e = tid; e < 256; e += 64) {
      const int q = e >> 6, u = (e >> 3) & 7, v = e & 7;
      float sr = 0.f, si = 0.f;
      #pragma unroll
      for (int i2 = 0; i2 < 2; ++i2)
        #pragma unroll
        for (int j2 = 0; j2 < 2; ++j2) {
          const int r = u + 8 * i2, c = v + 8 * j2;
          const float ph = P1[r * 17 + c];
          sr += Cr[q * 272 + r * 17 + c] * ph;
          si += Ci[q * 272 + r * 17 + c] * ph;
        }
      Sr[q * 72 + u * 9 + v] = 0.25f * sr;
      Si[q * 72 + u * 9 + v] = 0.25f * si;
    }
    __syncthreads();
    if (tid < 32) { const int q = tid >> 3, r = tid & 7; passN<8>(Sr + q * 72, Si + q * 72, r * 9, 1, 1.0f, 0, 0.0f); }
    __syncthreads();
    if (tid < 32) {
      const int q = tid >> 3, col = tid & 7;
      float2 a[8];
      #pragma unroll
      for (int i = 0; i < 8; ++i) a[i] = make_float2(Sr[q * 72 + i * 9 + col], Si[q * 72 + i * 9 + col]);
      fftN<8>(a, 1.0f);
      float* fo = feat + ((size_t)bc * 81 + chb + q) * 64;
      #pragma unroll
      for (int i = 0; i < 8; ++i) fo[i * 8 + col] = a[i].x * (1.0f / 64.0f);
    }
    __syncthreads();
  }
}

// ---------------------------------------------------------------------------
// k_gnlin: GroupNorm(27) + Linear(15552->10). grid 64, block 1024 (16 waves).
// ---------------------------------------------------------------------------
__global__ __launch_bounds__(1024) void k_gnlin(
    const float* __restrict__ feat, const float* __restrict__ gamma,
    const float* __restrict__ beta, const float* __restrict__ W,
    const float* __restrict__ bias, float* __restrict__ out)
{
  __shared__ __align__(16) float F[15552];
  __shared__ float gmu[27], grs[27];
  __shared__ float red[160];
  const int tid = threadIdx.x, b = blockIdx.x;
  const float4* fp4 = reinterpret_cast<const float4*>(feat + (size_t)b * 15552);
  float4* F4 = reinterpret_cast<float4*>(F);
  for (int i4 = tid; i4 < 3888; i4 += 1024) F4[i4] = fp4[i4];
  __syncthreads();
  if (tid < 432) {
    const int g = tid >> 4, l = tid & 15;
    float s = 0.f, ss = 0.f;
    for (int e = l; e < 576; e += 16) { const float v = F[g * 576 + e]; s += v; ss += v * v; }
    #pragma unroll
    for (int off = 1; off < 16; off <<= 1) { s += __shfl_xor(s, off, 16); ss += __shfl_xor(ss, off, 16); }
    if (l == 0) {
      const float mu = s * (1.0f / 576.0f);
      gmu[g] = mu;
      grs[g] = rsqrtf(ss * (1.0f / 576.0f) - mu * mu + 1e-5f);
    }
  }
  __syncthreads();
  for (int e = tid; e < 15552; e += 1024) {
    const int ch = e >> 6, g = ch / 9;
    F[e] = (F[e] - gmu[g]) * grs[g] * gamma[ch] + beta[ch];
  }
  __syncthreads();
  float acc[10];
  #pragma unroll
  for (int k = 0; k < 10; ++k) acc[k] = 0.f;
  const float4* W4 = reinterpret_cast<const float4*>(W);
  for (int i4 = tid; i4 < 3888; i4 += 1024) {
    const float4 f = F4[i4];
    #pragma unroll
    for (int k = 0; k < 10; ++k) {
      const float4 w = W4[(size_t)k * 3888 + i4];
      acc[k] = fmaf(f.x, w.x, fmaf(f.y, w.y, fmaf(f.z, w.z, fmaf(f.w, w.w, acc[k]))));
    }
  }
  #pragma unroll
  for (int k = 0; k < 10; ++k) {
    float v = acc[k];
    #pragma unroll
    for (int off = 32; off > 0; off >>= 1) v += __shfl_down(v, off);
    if ((tid & 63) == 0) red[(tid >> 6) * 10 + k] = v;
  }
  __syncthreads();
  if (tid < 10) {
    float s = bias[tid];
    #pragma unroll
    for (int w = 0; w < 16; ++w) s += red[w * 10 + tid];
    out[b * 10 + tid] = s;
  }
}

// ---------------------------------------------------------------------------
extern "C" void kernel_launch(void* const* d_in, const int* in_sizes, int n_in,
                              void* d_out, int out_size, void* d_ws, size_t ws_size,
                              hipStream_t stream) {
  (void)in_sizes; (void)n_in; (void)out_size; (void)ws_size;
  const float* x     = (const float*)d_in[0];
  const float* psi0  = (const float*)d_in[1];
  const float* psi1  = (const float*)d_in[2];
  const float* phi   = (const float*)d_in[3];
  const float* gamma = (const float*)d_in[4];
  const float* beta  = (const float*)d_in[5];
  const float* W     = (const float*)d_in[6];
  const float* bias  = (const float*)d_in[7];
  float* out = (float*)d_out;

  float* feat = (float*)d_ws;   // 64*15552 f32 = 4 MB

  hipLaunchKernelGGL(k_scat,  dim3(1152), dim3(64),   0, stream, x, psi0, psi1, phi, feat);
  hipLaunchKernelGGL(k_gnlin, dim3(64),   dim3(1024), 0, stream, feat, gamma, beta, W, bias, out);
}